// Round 6
// baseline (329.249 us; speedup 1.0000x reference)
//
#include <hip/hip_runtime.h>
#include <math.h>

#define B_ 2
#define S_ 2048
#define E_ 1024
#define H_ 16
#define HD_ 64
#define LAMBDA_INIT 0.8f
#define EPS_ 1e-6f

typedef __attribute__((ext_vector_type(8))) short short8;   // 8 bf16 (4 VGPRs)
typedef __attribute__((ext_vector_type(4))) float floatx4;  // MFMA C/D

__device__ __forceinline__ unsigned short f2bf(float f) {
  unsigned u = __float_as_uint(f);
  u += 0x7FFFu + ((u >> 16) & 1u);   // RNE
  return (unsigned short)(u >> 16);
}

__device__ __forceinline__ void gl_lds16(const void* g, void* l) {
  __builtin_amdgcn_global_load_lds((const __attribute__((address_space(1))) void*)g,
                                   (__attribute__((address_space(3))) void*)l,
                                   16, 0, 0);
}

// ---------------------------------------------------------------------------
// cast fp32 -> bf16, contiguous
// ---------------------------------------------------------------------------
__global__ __launch_bounds__(256) void cast_bf16(const float* __restrict__ in,
                                                 unsigned short* __restrict__ out,
                                                 int n4) {
  for (int i = blockIdx.x * 256 + threadIdx.x; i < n4; i += gridDim.x * 256) {
    float4 v = ((const float4*)in)[i];
    ushort4 w;
    w.x = f2bf(v.x); w.y = f2bf(v.y); w.z = f2bf(v.z); w.w = f2bf(v.w);
    ((ushort4*)out)[i] = w;
  }
}

// ---------------------------------------------------------------------------
// transpose + cast: in fp32 [R][C] -> out bf16 [C][R]
// ---------------------------------------------------------------------------
__global__ __launch_bounds__(256) void transpose_cast(const float* __restrict__ in,
                                                      unsigned short* __restrict__ out,
                                                      int R, int C) {
  __shared__ float tile[64][65];
  const int tid = threadIdx.x;
  const int c0 = blockIdx.x * 64;
  const int r0 = blockIdx.y * 64;
#pragma unroll
  for (int it = 0; it < 16; it++) {
    int e = tid + it * 256;
    int rr = e >> 6, cc = e & 63;
    tile[rr][cc] = in[(size_t)(r0 + rr) * C + c0 + cc];
  }
  __syncthreads();
#pragma unroll
  for (int it = 0; it < 16; it++) {
    int e = tid + it * 256;
    int rr = e >> 6, cc = e & 63;
    out[(size_t)(c0 + rr) * R + r0 + cc] = f2bf(tile[cc][rr]);
  }
}

// ---------------------------------------------------------------------------
// bf16 MFMA GEMM: C[M][N] = A[M][K] @ B[K][N], B given TRANSPOSED as Bt[N][K].
// 128x128 tile, BK=64, global_load_lds w=16, XOR chunk swizzle.
// ---------------------------------------------------------------------------
template <bool BF16OUT>
__global__ __launch_bounds__(256) void gemm_bt(const unsigned short* __restrict__ A,
                                               const unsigned short* __restrict__ Bt,
                                               void* __restrict__ C,
                                               int M, int N, int K) {
  __shared__ __align__(16) unsigned short As[128 * 64];
  __shared__ __align__(16) unsigned short Bs[128 * 64];
  const int tid = threadIdx.x;
  const int wave = tid >> 6, lane = tid & 63;
  const int lane15 = lane & 15, quad = lane >> 4;
  const int m0 = blockIdx.y * 128;
  const int n0 = blockIdx.x * 128;
  const int wm = (wave & 1) * 64, wn = (wave >> 1) * 64;

  floatx4 acc[4][4];
#pragma unroll
  for (int mi = 0; mi < 4; mi++)
#pragma unroll
    for (int ni = 0; ni < 4; ni++) acc[mi][ni] = (floatx4)0.0f;

  const int rs = wave * 32 + (lane >> 3);
  const int cph = lane & 7;

  for (int k0 = 0; k0 < K; k0 += 64) {
    __syncthreads();
#pragma unroll
    for (int j = 0; j < 4; j++) {
      int r = rs + j * 8;
      int cl = cph ^ (r & 7);
      gl_lds16(A + (size_t)(m0 + r) * K + k0 + cl * 8, &As[(wave * 32 + j * 8) * 64]);
    }
#pragma unroll
    for (int j = 0; j < 4; j++) {
      int r = rs + j * 8;
      int cl = cph ^ (r & 7);
      gl_lds16(Bt + (size_t)(n0 + r) * K + k0 + cl * 8, &Bs[(wave * 32 + j * 8) * 64]);
    }
    __syncthreads();

#pragma unroll
    for (int ks = 0; ks < 2; ks++) {
      short8 af[4], bf[4];
#pragma unroll
      for (int mi = 0; mi < 4; mi++) {
        int r = wm + mi * 16 + lane15;
        int phys = (ks * 4 + quad) ^ (r & 7);
        af[mi] = *(const short8*)(&As[r * 64 + phys * 8]);
      }
#pragma unroll
      for (int ni = 0; ni < 4; ni++) {
        int r = wn + ni * 16 + lane15;
        int phys = (ks * 4 + quad) ^ (r & 7);
        bf[ni] = *(const short8*)(&Bs[r * 64 + phys * 8]);
      }
#pragma unroll
      for (int mi = 0; mi < 4; mi++)
#pragma unroll
        for (int ni = 0; ni < 4; ni++)
          acc[mi][ni] = __builtin_amdgcn_mfma_f32_16x16x32_bf16(af[mi], bf[ni],
                                                                acc[mi][ni], 0, 0, 0);
    }
  }

#pragma unroll
  for (int mi = 0; mi < 4; mi++)
#pragma unroll
    for (int ni = 0; ni < 4; ni++)
#pragma unroll
      for (int reg = 0; reg < 4; reg++) {
        int row = m0 + wm + mi * 16 + quad * 4 + reg;
        int col = n0 + wn + ni * 16 + lane15;
        float v = acc[mi][ni][reg];
        if (BF16OUT)
          ((unsigned short*)C)[(size_t)row * N + col] = f2bf(v);
        else
          ((float*)C)[(size_t)row * N + col] = v;
      }
}

// ---------------------------------------------------------------------------
// S^T-form MFMA flash differential attention, software-pipelined.
// Manual uint4 staging with explicit t+1 register prefetch. Dual P buffers.
// XOR chunk swizzle (phys = logical ^ (row&7)) throughout.
// NOTE: no min-waves launch bound — R5's (256,4) capped VGPR at 128 and
// forced per-tile scratch spills of the prefetch registers (WRITE_SIZE
// 16 MB -> 284 MB). Let the allocator take ~120-160 VGPRs; LDS (40 KB)
// still allows 4 blocks/CU.
// ---------------------------------------------------------------------------
__global__ __launch_bounds__(256) void flash_attn_mfma(
    const unsigned short* __restrict__ qkB, const unsigned short* __restrict__ vTB,
    const float* __restrict__ lq1, const float* __restrict__ lq2,
    const float* __restrict__ lk1, const float* __restrict__ lk2,
    const float* __restrict__ norm_w, float* __restrict__ out_n) {
  __shared__ __align__(16) unsigned short Qs[64 * 64];
  __shared__ __align__(16) unsigned short Ks[64 * 64];
  __shared__ __align__(16) unsigned short Vt[64 * 64];
  __shared__ __align__(16) unsigned short Ps0[64 * 64];
  __shared__ __align__(16) unsigned short Ps1[64 * 64];

  const int tid = threadIdx.x;
  const int wave = tid >> 6, lane = tid & 63;
  const int lane15 = lane & 15, quad = lane >> 4;
  const int m7 = lane15 & 7;
  const int bid = blockIdx.x;          // 1024 = B*H*32
  const int qt = bid & 31;
  const int h = (bid >> 5) & 15;
  const int b = bid >> 9;
  const int q0 = qt * 64;

  float a1 = 0.f, a2 = 0.f;
  for (int d = 0; d < HD_; d++) {
    a1 += lq1[d] * lk1[d];
    a2 += lq2[d] * lk2[d];
  }
  const float lam = __expf(a1) - __expf(a2) + LAMBDA_INIT;

  // staging geometry: thread covers rows r = (tid>>3) + it*32, phys chunk tid&7
  const int sr = tid >> 3;          // 0..31
  const int sp = tid & 7;           // physical chunk

  // ---- stage Q ----
#pragma unroll
  for (int it = 0; it < 2; it++) {
    int r = sr + it * 32;
    int cl = sp ^ (r & 7);
    uint4 v = *(const uint4*)(qkB + (size_t)(b * S_ + q0 + r) * 2048 + h * 64 + cl * 8);
    *(uint4*)(Qs + r * 64 + sp * 8) = v;
  }

  const size_t kgbase = (size_t)b * S_ * 2048 + 1024 + h * 64;
  const size_t vgbase = (size_t)h * 64 * 4096 + b * 2048;

  // prefetch tile 0 K/V into registers
  uint4 kreg[2], vreg[2];
#pragma unroll
  for (int it = 0; it < 2; it++) {
    int r = sr + it * 32;
    int cl = sp ^ (r & 7);
    kreg[it] = *(const uint4*)(qkB + kgbase + (size_t)r * 2048 + cl * 8);
    vreg[it] = *(const uint4*)(vTB + vgbase + (size_t)r * 4096 + cl * 8);
  }
  __syncthreads();   // Qs visible

  const int myrow = wave * 16 + lane15;
  // Q as B-operand: B[n=q][k=d], logical chunk quad / 4+quad
  const short8 bq0 = *(const short8*)(Qs + myrow * 64 + ((quad) ^ m7) * 8);
  const short8 bq1 = *(const short8*)(Qs + myrow * 64 + ((4 + quad) ^ m7) * 8);

  floatx4 accO[2][4];   // [stream][nd]; D[q=quad*4+reg][d=nd*16+lane15]
  float lsum[2] = {0.f, 0.f};
#pragma unroll
  for (int s = 0; s < 2; s++)
#pragma unroll
    for (int nd = 0; nd < 4; nd++) accO[s][nd] = (floatx4)0.0f;
  const floatx4 zero4 = (floatx4)0.0f;

  for (int t0 = 0; t0 < S_; t0 += 64) {
    __syncthreads();   // prior tile's frag reads done
#pragma unroll
    for (int it = 0; it < 2; it++) {
      int r = sr + it * 32;
      *(uint4*)(Ks + r * 64 + sp * 8) = kreg[it];
      *(uint4*)(Vt + r * 64 + sp * 8) = vreg[it];
    }
    __syncthreads();   // staged data visible

    // issue next tile's loads (hide HBM/L2 latency under this tile's compute)
    if (t0 + 64 < S_) {
#pragma unroll
      for (int it = 0; it < 2; it++) {
        int r = sr + it * 32;
        int cl = sp ^ (r & 7);
        kreg[it] = *(const uint4*)(qkB + kgbase + (size_t)(t0 + 64 + r) * 2048 + cl * 8);
        vreg[it] = *(const uint4*)(vTB + vgbase + (size_t)r * 4096 + t0 + 64 + cl * 8);
      }
    }

    short8 ap[2][2];   // A-frags of P for both streams
#pragma unroll
    for (int s = 0; s < 2; s++) {
      const short8 bq = s ? bq1 : bq0;
      unsigned short* Ps = s ? Ps1 : Ps0;
      floatx4 sv[4];
#pragma unroll
      for (int nb = 0; nb < 4; nb++) {
        const short8 ak = *(const short8*)(Ks + (nb * 16 + lane15) * 64 +
                                           ((s * 4 + quad) ^ m7) * 8);
        sv[nb] = __builtin_amdgcn_mfma_f32_16x16x32_bf16(ak, bq, zero4, 0, 0, 0);
      }
      // exp + pack: lane holds S^T[t=nb*16+quad*4+reg][q=lane15]
      float ls = 0.f;
#pragma unroll
      for (int nb = 0; nb < 4; nb++) {
        float p0 = __expf(sv[nb][0] * 0.125f);
        float p1 = __expf(sv[nb][1] * 0.125f);
        float p2 = __expf(sv[nb][2] * 0.125f);
        float p3 = __expf(sv[nb][3] * 0.125f);
        ls += (p0 + p1) + (p2 + p3);
        unsigned lo = (unsigned)f2bf(p0) | ((unsigned)f2bf(p1) << 16);
        unsigned hi = (unsigned)f2bf(p2) | ((unsigned)f2bf(p3) << 16);
        int cl = nb * 2 + (quad >> 1);
        uint2* dst = (uint2*)(Ps + myrow * 64 + ((cl ^ m7) * 8) + (quad & 1) * 4);
        *dst = make_uint2(lo, hi);
      }
      lsum[s] += ls;
    }
    // read A-frags of P (own wave's rows; ordering via lgkmcnt)
#pragma unroll
    for (int s = 0; s < 2; s++) {
      const unsigned short* Ps = s ? Ps1 : Ps0;
#pragma unroll
      for (int ks = 0; ks < 2; ks++)
        ap[s][ks] = *(const short8*)(Ps + myrow * 64 + ((ks * 4 + quad) ^ m7) * 8);
    }
    // PV: V^T frag read once per (ks,nd), shared by both streams
#pragma unroll
    for (int ks = 0; ks < 2; ks++)
#pragma unroll
      for (int nd = 0; nd < 4; nd++) {
        const short8 bv = *(const short8*)(Vt + (nd * 16 + lane15) * 64 +
                                           ((ks * 4 + quad) ^ m7) * 8);
        accO[0][nd] = __builtin_amdgcn_mfma_f32_16x16x32_bf16(ap[0][ks], bv,
                                                              accO[0][nd], 0, 0, 0);
        accO[1][nd] = __builtin_amdgcn_mfma_f32_16x16x32_bf16(ap[1][ks], bv,
                                                              accO[1][nd], 0, 0, 0);
      }
  }

  // ---- epilogue ----
#pragma unroll
  for (int s = 0; s < 2; s++) {
    lsum[s] += __shfl_xor(lsum[s], 16, 64);
    lsum[s] += __shfl_xor(lsum[s], 32, 64);
  }
  const float* nw = norm_w + h * HD_;
  float nwv[4];
#pragma unroll
  for (int nd = 0; nd < 4; nd++) nwv[nd] = nw[nd * 16 + lane15];

#pragma unroll
  for (int r4 = 0; r4 < 4; r4++) {
    const int qloc = quad * 4 + r4;
    const float l1 = __shfl(lsum[0], qloc, 64);
    const float l2 = __shfl(lsum[1], qloc, 64);
    const float inv1 = 1.0f / l1;
    const float c2 = lam / l2;
    float o[4];
    float ss = 0.f;
#pragma unroll
    for (int nd = 0; nd < 4; nd++) {
      o[nd] = accO[0][nd][r4] * inv1 - accO[1][nd][r4] * c2;
      ss += o[nd] * o[nd];
    }
#pragma unroll
    for (int msk = 1; msk <= 8; msk <<= 1) ss += __shfl_xor(ss, msk, 64);
    const float rsc = (1.0f - LAMBDA_INIT) * rsqrtf(ss * (1.0f / 64.0f) + EPS_);
    const int trow = q0 + wave * 16 + qloc;
    float* dst = out_n + ((size_t)(b * H_ + h) * S_ + trow) * HD_;
#pragma unroll
    for (int nd = 0; nd < 4; nd++)
      dst[nd * 16 + lane15] = o[nd] * rsc * nwv[nd];
  }
}

// ---------------------------------------------------------------------------
// Reshape out_n [B,H,S,HD] fp32 -> hidden bf16 (reference cat/transpose/view)
// ---------------------------------------------------------------------------
__global__ __launch_bounds__(256) void reshape_out(const float* __restrict__ out_n,
                                                   unsigned short* __restrict__ hidden) {
  __shared__ float tile[64][65];
  const int tid = threadIdx.x;
  const int bi = blockIdx.x;  // B*H*32 = 1024
  const int tb = bi & 31;
  const int h = (bi >> 5) & 15;
  const int b = bi >> 9;
  const int t0 = tb * 64;
  const float* src = out_n + (((size_t)b * H_ + h) * S_ + t0) * HD_;
#pragma unroll
  for (int rr = 0; rr < 16; rr++) {
    int e = tid + rr * 256;
    tile[e >> 6][e & 63] = src[e];
  }
  __syncthreads();
  unsigned short* dst = hidden + (size_t)b * (S_ * E_) + h * S_ + t0;
#pragma unroll
  for (int rr = 0; rr < 16; rr++) {
    int e = tid + rr * 256;
    int d = e >> 6, tt = e & 63;
    dst[(size_t)d * (H_ * S_) + tt] = f2bf(tile[tt][d]);
  }
}

// ---------------------------------------------------------------------------
extern "C" void kernel_launch(void* const* d_in, const int* in_sizes, int n_in,
                              void* d_out, int out_size, void* d_ws, size_t ws_size,
                              hipStream_t stream) {
  const float* x = (const float*)d_in[0];
  const float* w_qkv = (const float*)d_in[1];
  const float* wo = (const float*)d_in[2];
  const float* lq1 = (const float*)d_in[3];
  const float* lq2 = (const float*)d_in[4];
  const float* lk1 = (const float*)d_in[5];
  const float* lk2 = (const float*)d_in[6];
  const float* norm_w = (const float*)d_in[7];
  float* out = (float*)d_out;

  unsigned short* xB = (unsigned short*)d_ws;             // 4096*1024
  unsigned short* WT = xB + (size_t)4096 * 1024;          // 3072*1024 (w_qkv^T)
  unsigned short* woT = WT + (size_t)3072 * 1024;         // 1024*1024
  unsigned short* qkB = woT + (size_t)1024 * 1024;        // 4096*2048
  unsigned short* vTB = qkB + (size_t)4096 * 2048;        // 1024*4096
  unsigned short* hidB = vTB + (size_t)1024 * 4096;       // 4096*1024
  float* out_n = (float*)(hidB + (size_t)4096 * 1024);    // 4 Mi floats

  // 0) bf16 casts / transposes of inputs
  cast_bf16<<<1024, 256, 0, stream>>>(x, xB, 4096 * 1024 / 4);
  transpose_cast<<<dim3(48, 16), 256, 0, stream>>>(w_qkv, WT, 1024, 3072);
  transpose_cast<<<dim3(16, 16), 256, 0, stream>>>(wo, woT, 1024, 1024);

  // 1a) q,k = x @ Wqk      -> qkB bf16 [4096][2048]
  gemm_bt<true><<<dim3(2048 / 128, 4096 / 128), 256, 0, stream>>>(
      xB, WT, (void*)qkB, 4096, 2048, 1024);
  // 1b) vT = Wv^T @ x^T    -> vTB bf16 [1024][4096]  (operand swap: free transpose)
  gemm_bt<true><<<dim3(4096 / 128, 1024 / 128), 256, 0, stream>>>(
      WT + (size_t)2048 * 1024, xB, (void*)vTB, 1024, 4096, 1024);

  // 2) MFMA differential flash attention + RMSNorm
  flash_attn_mfma<<<B_ * H_ * (S_ / 64), 256, 0, stream>>>(qkB, vTB, lq1, lq2, lk1,
                                                           lk2, norm_w, out_n);
  // 3) reshape per reference's cat/transpose/view -> bf16
  reshape_out<<<B_ * H_ * (S_ / 64), 256, 0, stream>>>(out_n, hidB);
  // 4) out = hidden @ wo (fp32 out)
  gemm_bt<false><<<dim3(1024 / 128, 4096 / 128), 256, 0, stream>>>(
      hidB, woT, (void*)out, 4096, 1024, 1024);
}

// Round 7
// 297.531 us; speedup vs baseline: 1.1066x; 1.1066x over previous
//
#include <hip/hip_runtime.h>
#include <math.h>

#define B_ 2
#define S_ 2048
#define E_ 1024
#define H_ 16
#define HD_ 64
#define LAMBDA_INIT 0.8f
#define EPS_ 1e-6f

typedef __attribute__((ext_vector_type(8))) short short8;   // 8 bf16 (4 VGPRs)
typedef __attribute__((ext_vector_type(4))) float floatx4;  // MFMA C/D

__device__ __forceinline__ unsigned short f2bf(float f) {
  unsigned u = __float_as_uint(f);
  u += 0x7FFFu + ((u >> 16) & 1u);   // RNE
  return (unsigned short)(u >> 16);
}

__device__ __forceinline__ void gl_lds16(const void* g, void* l) {
  __builtin_amdgcn_global_load_lds((const __attribute__((address_space(1))) void*)g,
                                   (__attribute__((address_space(3))) void*)l,
                                   16, 0, 0);
}

// ---------------------------------------------------------------------------
// cast fp32 -> bf16, contiguous
// ---------------------------------------------------------------------------
__global__ __launch_bounds__(256) void cast_bf16(const float* __restrict__ in,
                                                 unsigned short* __restrict__ out,
                                                 int n4) {
  for (int i = blockIdx.x * 256 + threadIdx.x; i < n4; i += gridDim.x * 256) {
    float4 v = ((const float4*)in)[i];
    ushort4 w;
    w.x = f2bf(v.x); w.y = f2bf(v.y); w.z = f2bf(v.z); w.w = f2bf(v.w);
    ((ushort4*)out)[i] = w;
  }
}

// ---------------------------------------------------------------------------
// transpose + cast: in fp32 [R][C] -> out bf16 [C][R]
// ---------------------------------------------------------------------------
__global__ __launch_bounds__(256) void transpose_cast(const float* __restrict__ in,
                                                      unsigned short* __restrict__ out,
                                                      int R, int C) {
  __shared__ float tile[64][65];
  const int tid = threadIdx.x;
  const int c0 = blockIdx.x * 64;
  const int r0 = blockIdx.y * 64;
#pragma unroll
  for (int it = 0; it < 16; it++) {
    int e = tid + it * 256;
    int rr = e >> 6, cc = e & 63;
    tile[rr][cc] = in[(size_t)(r0 + rr) * C + c0 + cc];
  }
  __syncthreads();
#pragma unroll
  for (int it = 0; it < 16; it++) {
    int e = tid + it * 256;
    int rr = e >> 6, cc = e & 63;
    out[(size_t)(c0 + rr) * R + r0 + cc] = f2bf(tile[cc][rr]);
  }
}

// ---------------------------------------------------------------------------
// bf16 MFMA GEMM: C[M][N] = A[M][K] @ B[K][N], B given TRANSPOSED as Bt[N][K].
// 128x128 tile, BK=64, global_load_lds w=16, XOR chunk swizzle.
// ---------------------------------------------------------------------------
template <bool BF16OUT>
__global__ __launch_bounds__(256) void gemm_bt(const unsigned short* __restrict__ A,
                                               const unsigned short* __restrict__ Bt,
                                               void* __restrict__ C,
                                               int M, int N, int K) {
  __shared__ __align__(16) unsigned short As[128 * 64];
  __shared__ __align__(16) unsigned short Bs[128 * 64];
  const int tid = threadIdx.x;
  const int wave = tid >> 6, lane = tid & 63;
  const int lane15 = lane & 15, quad = lane >> 4;
  const int m0 = blockIdx.y * 128;
  const int n0 = blockIdx.x * 128;
  const int wm = (wave & 1) * 64, wn = (wave >> 1) * 64;

  floatx4 acc[4][4];
#pragma unroll
  for (int mi = 0; mi < 4; mi++)
#pragma unroll
    for (int ni = 0; ni < 4; ni++) acc[mi][ni] = (floatx4)0.0f;

  const int rs = wave * 32 + (lane >> 3);
  const int cph = lane & 7;

  for (int k0 = 0; k0 < K; k0 += 64) {
    __syncthreads();
#pragma unroll
    for (int j = 0; j < 4; j++) {
      int r = rs + j * 8;
      int cl = cph ^ (r & 7);
      gl_lds16(A + (size_t)(m0 + r) * K + k0 + cl * 8, &As[(wave * 32 + j * 8) * 64]);
    }
#pragma unroll
    for (int j = 0; j < 4; j++) {
      int r = rs + j * 8;
      int cl = cph ^ (r & 7);
      gl_lds16(Bt + (size_t)(n0 + r) * K + k0 + cl * 8, &Bs[(wave * 32 + j * 8) * 64]);
    }
    __syncthreads();

#pragma unroll
    for (int ks = 0; ks < 2; ks++) {
      short8 af[4], bf[4];
#pragma unroll
      for (int mi = 0; mi < 4; mi++) {
        int r = wm + mi * 16 + lane15;
        int phys = (ks * 4 + quad) ^ (r & 7);
        af[mi] = *(const short8*)(&As[r * 64 + phys * 8]);
      }
#pragma unroll
      for (int ni = 0; ni < 4; ni++) {
        int r = wn + ni * 16 + lane15;
        int phys = (ks * 4 + quad) ^ (r & 7);
        bf[ni] = *(const short8*)(&Bs[r * 64 + phys * 8]);
      }
#pragma unroll
      for (int mi = 0; mi < 4; mi++)
#pragma unroll
        for (int ni = 0; ni < 4; ni++)
          acc[mi][ni] = __builtin_amdgcn_mfma_f32_16x16x32_bf16(af[mi], bf[ni],
                                                                acc[mi][ni], 0, 0, 0);
    }
  }

#pragma unroll
  for (int mi = 0; mi < 4; mi++)
#pragma unroll
    for (int ni = 0; ni < 4; ni++)
#pragma unroll
      for (int reg = 0; reg < 4; reg++) {
        int row = m0 + wm + mi * 16 + quad * 4 + reg;
        int col = n0 + wn + ni * 16 + lane15;
        float v = acc[mi][ni][reg];
        if (BF16OUT)
          ((unsigned short*)C)[(size_t)row * N + col] = f2bf(v);
        else
          ((float*)C)[(size_t)row * N + col] = v;
      }
}

// ---------------------------------------------------------------------------
// S^T-form MFMA flash differential attention, DMA double-buffered.
// K/V of tile t+1 DMA'd (global_load_lds, zero registers) into the alternate
// LDS buffers while tile t computes; single __syncthreads per iteration whose
// vmcnt drain lands AFTER compute. Single Ps (wave-private rows, in-order DS).
// XOR chunk swizzle phys = logical ^ (row&7) throughout.
// History: R4 DMA same-buffer = serialized (158us); R5/R6 register prefetch
// = allocator spills it to scratch (WRITE_SIZE 300 MB, 185us). This keeps
// prefetch in LDS with no cross-compute register state.
// ---------------------------------------------------------------------------
__global__ __launch_bounds__(256) void flash_attn_mfma(
    const unsigned short* __restrict__ qkB, const unsigned short* __restrict__ vTB,
    const float* __restrict__ lq1, const float* __restrict__ lq2,
    const float* __restrict__ lk1, const float* __restrict__ lk2,
    const float* __restrict__ norm_w, float* __restrict__ out_n) {
  __shared__ __align__(16) unsigned short Qs[64 * 64];
  __shared__ __align__(16) unsigned short Ks[2][64 * 64];
  __shared__ __align__(16) unsigned short Vt[2][64 * 64];
  __shared__ __align__(16) unsigned short Ps[64 * 64];

  const int tid = threadIdx.x;
  const int wave = tid >> 6, lane = tid & 63;
  const int lane15 = lane & 15, quad = lane >> 4;
  const int m7 = lane15 & 7;
  const int bid = blockIdx.x;          // 1024 = B*H*32
  const int qt = bid & 31;
  const int h = (bid >> 5) & 15;
  const int b = bid >> 9;
  const int q0 = qt * 64;

  float a1 = 0.f, a2 = 0.f;
  for (int d = 0; d < HD_; d++) {
    a1 += lq1[d] * lk1[d];
    a2 += lq2[d] * lk2[d];
  }
  const float lam = __expf(a1) - __expf(a2) + LAMBDA_INIT;

  // DMA staging geometry (per wave, j=0..1): rows wave*16 + j*8 + (lane>>3),
  // LDS dest = base + lane*16 (HW-fixed) -> phys chunk lane&7; global logical
  // chunk scl = (lane&7) ^ srow so that phys = logical ^ (row&7).
  const int srow = lane >> 3;
  const int scl = (lane & 7) ^ srow;

  const size_t kgbase = (size_t)b * S_ * 2048 + 1024 + h * 64;
  const size_t vgbase = (size_t)h * 64 * 4096 + b * 2048;

  // ---- stage Q (manual) + DMA tile 0 into buffer 0, one barrier ----
  {
    const int sr = tid >> 3, sp = tid & 7;
#pragma unroll
    for (int it = 0; it < 2; it++) {
      int r = sr + it * 32;
      int cl = sp ^ (r & 7);
      uint4 v = *(const uint4*)(qkB + (size_t)(b * S_ + q0 + r) * 2048 + h * 64 + cl * 8);
      *(uint4*)(Qs + r * 64 + sp * 8) = v;
    }
  }
#pragma unroll
  for (int j = 0; j < 2; j++) {
    int r = wave * 16 + j * 8 + srow;
    gl_lds16(qkB + kgbase + (size_t)r * 2048 + scl * 8, &Ks[0][(wave * 16 + j * 8) * 64]);
    gl_lds16(vTB + vgbase + (size_t)r * 4096 + scl * 8, &Vt[0][(wave * 16 + j * 8) * 64]);
  }
  __syncthreads();   // Qs visible + tile0 DMA drained

  const int myrow = wave * 16 + lane15;
  // Q as B-operand: B[n=q][k=d], logical chunk quad / 4+quad
  const short8 bq0 = *(const short8*)(Qs + myrow * 64 + ((quad) ^ m7) * 8);
  const short8 bq1 = *(const short8*)(Qs + myrow * 64 + ((4 + quad) ^ m7) * 8);

  floatx4 accO[2][4];   // [stream][nd]; D[q=quad*4+reg][d=nd*16+lane15]
  float lsum[2] = {0.f, 0.f};
#pragma unroll
  for (int s = 0; s < 2; s++)
#pragma unroll
    for (int nd = 0; nd < 4; nd++) accO[s][nd] = (floatx4)0.0f;
  const floatx4 zero4 = (floatx4)0.0f;

  for (int tt = 0; tt < 32; tt++) {
    const int cur = tt & 1, nxt = cur ^ 1;
    // issue next tile's DMA into the other buffer (overlaps this tile's compute)
    if (tt + 1 < 32) {
      const int t1 = (tt + 1) * 64;
#pragma unroll
      for (int j = 0; j < 2; j++) {
        int r = wave * 16 + j * 8 + srow;
        gl_lds16(qkB + kgbase + (size_t)(t1 + r) * 2048 + scl * 8,
                 &Ks[nxt][(wave * 16 + j * 8) * 64]);
        gl_lds16(vTB + vgbase + (size_t)r * 4096 + t1 + scl * 8,
                 &Vt[nxt][(wave * 16 + j * 8) * 64]);
      }
    }

    const unsigned short* Kc = Ks[cur];
    const unsigned short* Vc = Vt[cur];
#pragma unroll
    for (int s = 0; s < 2; s++) {
      const short8 bq = s ? bq1 : bq0;
      floatx4 sv[4];
#pragma unroll
      for (int nb = 0; nb < 4; nb++) {
        const short8 ak = *(const short8*)(Kc + (nb * 16 + lane15) * 64 +
                                           ((s * 4 + quad) ^ m7) * 8);
        sv[nb] = __builtin_amdgcn_mfma_f32_16x16x32_bf16(ak, bq, zero4, 0, 0, 0);
      }
      // exp + pack: lane holds S^T[t=nb*16+quad*4+reg][q=lane15]
      float ls = 0.f;
#pragma unroll
      for (int nb = 0; nb < 4; nb++) {
        float p0 = __expf(sv[nb][0] * 0.125f);
        float p1 = __expf(sv[nb][1] * 0.125f);
        float p2 = __expf(sv[nb][2] * 0.125f);
        float p3 = __expf(sv[nb][3] * 0.125f);
        ls += (p0 + p1) + (p2 + p3);
        unsigned lo = (unsigned)f2bf(p0) | ((unsigned)f2bf(p1) << 16);
        unsigned hi = (unsigned)f2bf(p2) | ((unsigned)f2bf(p3) << 16);
        int cl = nb * 2 + (quad >> 1);
        uint2* dst = (uint2*)(Ps + myrow * 64 + ((cl ^ m7) * 8) + (quad & 1) * 4);
        *dst = make_uint2(lo, hi);
      }
      lsum[s] += ls;
      // PV: A = P row myrow (own wave's write, in-order DS), B = V^T
#pragma unroll
      for (int ks = 0; ks < 2; ks++) {
        const short8 ap = *(const short8*)(Ps + myrow * 64 + ((ks * 4 + quad) ^ m7) * 8);
#pragma unroll
        for (int nd = 0; nd < 4; nd++) {
          const short8 bv = *(const short8*)(Vc + (nd * 16 + lane15) * 64 +
                                             ((ks * 4 + quad) ^ m7) * 8);
          accO[s][nd] = __builtin_amdgcn_mfma_f32_16x16x32_bf16(ap, bv,
                                                                accO[s][nd], 0, 0, 0);
        }
      }
    }
    // single barrier: waits compute reads of cur AND drains next-tile DMA
    __syncthreads();
  }

  // ---- epilogue ----
#pragma unroll
  for (int s = 0; s < 2; s++) {
    lsum[s] += __shfl_xor(lsum[s], 16, 64);
    lsum[s] += __shfl_xor(lsum[s], 32, 64);
  }
  const float* nw = norm_w + h * HD_;
  float nwv[4];
#pragma unroll
  for (int nd = 0; nd < 4; nd++) nwv[nd] = nw[nd * 16 + lane15];

#pragma unroll
  for (int r4 = 0; r4 < 4; r4++) {
    const int qloc = quad * 4 + r4;
    const float l1 = __shfl(lsum[0], qloc, 64);
    const float l2 = __shfl(lsum[1], qloc, 64);
    const float inv1 = 1.0f / l1;
    const float c2 = lam / l2;
    float o[4];
    float ss = 0.f;
#pragma unroll
    for (int nd = 0; nd < 4; nd++) {
      o[nd] = accO[0][nd][r4] * inv1 - accO[1][nd][r4] * c2;
      ss += o[nd] * o[nd];
    }
#pragma unroll
    for (int msk = 1; msk <= 8; msk <<= 1) ss += __shfl_xor(ss, msk, 64);
    const float rsc = (1.0f - LAMBDA_INIT) * rsqrtf(ss * (1.0f / 64.0f) + EPS_);
    const int trow = q0 + wave * 16 + qloc;
    float* dst = out_n + ((size_t)(b * H_ + h) * S_ + trow) * HD_;
#pragma unroll
    for (int nd = 0; nd < 4; nd++)
      dst[nd * 16 + lane15] = o[nd] * rsc * nwv[nd];
  }
}

// ---------------------------------------------------------------------------
// Reshape out_n [B,H,S,HD] fp32 -> hidden bf16 (reference cat/transpose/view)
// ---------------------------------------------------------------------------
__global__ __launch_bounds__(256) void reshape_out(const float* __restrict__ out_n,
                                                   unsigned short* __restrict__ hidden) {
  __shared__ float tile[64][65];
  const int tid = threadIdx.x;
  const int bi = blockIdx.x;  // B*H*32 = 1024
  const int tb = bi & 31;
  const int h = (bi >> 5) & 15;
  const int b = bi >> 9;
  const int t0 = tb * 64;
  const float* src = out_n + (((size_t)b * H_ + h) * S_ + t0) * HD_;
#pragma unroll
  for (int rr = 0; rr < 16; rr++) {
    int e = tid + rr * 256;
    tile[e >> 6][e & 63] = src[e];
  }
  __syncthreads();
  unsigned short* dst = hidden + (size_t)b * (S_ * E_) + h * S_ + t0;
#pragma unroll
  for (int rr = 0; rr < 16; rr++) {
    int e = tid + rr * 256;
    int d = e >> 6, tt = e & 63;
    dst[(size_t)d * (H_ * S_) + tt] = f2bf(tile[tt][d]);
  }
}

// ---------------------------------------------------------------------------
extern "C" void kernel_launch(void* const* d_in, const int* in_sizes, int n_in,
                              void* d_out, int out_size, void* d_ws, size_t ws_size,
                              hipStream_t stream) {
  const float* x = (const float*)d_in[0];
  const float* w_qkv = (const float*)d_in[1];
  const float* wo = (const float*)d_in[2];
  const float* lq1 = (const float*)d_in[3];
  const float* lq2 = (const float*)d_in[4];
  const float* lk1 = (const float*)d_in[5];
  const float* lk2 = (const float*)d_in[6];
  const float* norm_w = (const float*)d_in[7];
  float* out = (float*)d_out;

  unsigned short* xB = (unsigned short*)d_ws;             // 4096*1024
  unsigned short* WT = xB + (size_t)4096 * 1024;          // 3072*1024 (w_qkv^T)
  unsigned short* woT = WT + (size_t)3072 * 1024;         // 1024*1024
  unsigned short* qkB = woT + (size_t)1024 * 1024;        // 4096*2048
  unsigned short* vTB = qkB + (size_t)4096 * 2048;        // 1024*4096
  unsigned short* hidB = vTB + (size_t)1024 * 4096;       // 4096*1024
  float* out_n = (float*)(hidB + (size_t)4096 * 1024);    // 4 Mi floats

  // 0) bf16 casts / transposes of inputs
  cast_bf16<<<1024, 256, 0, stream>>>(x, xB, 4096 * 1024 / 4);
  transpose_cast<<<dim3(48, 16), 256, 0, stream>>>(w_qkv, WT, 1024, 3072);
  transpose_cast<<<dim3(16, 16), 256, 0, stream>>>(wo, woT, 1024, 1024);

  // 1a) q,k = x @ Wqk      -> qkB bf16 [4096][2048]
  gemm_bt<true><<<dim3(2048 / 128, 4096 / 128), 256, 0, stream>>>(
      xB, WT, (void*)qkB, 4096, 2048, 1024);
  // 1b) vT = Wv^T @ x^T    -> vTB bf16 [1024][4096]  (operand swap: free transpose)
  gemm_bt<true><<<dim3(4096 / 128, 1024 / 128), 256, 0, stream>>>(
      WT + (size_t)2048 * 1024, xB, (void*)vTB, 1024, 4096, 1024);

  // 2) MFMA differential flash attention + RMSNorm
  flash_attn_mfma<<<B_ * H_ * (S_ / 64), 256, 0, stream>>>(qkB, vTB, lq1, lq2, lk1,
                                                           lk2, norm_w, out_n);
  // 3) reshape per reference's cat/transpose/view -> bf16
  reshape_out<<<B_ * H_ * (S_ / 64), 256, 0, stream>>>(out_n, hidB);
  // 4) out = hidden @ wo (fp32 out)
  gemm_bt<false><<<dim3(1024 / 128, 4096 / 128), 256, 0, stream>>>(
      hidB, woT, (void*)out, 4096, 1024, 1024);
}

// Round 8
// 296.925 us; speedup vs baseline: 1.1089x; 1.0020x over previous
//
#include <hip/hip_runtime.h>
#include <math.h>

#define B_ 2
#define S_ 2048
#define E_ 1024
#define H_ 16
#define HD_ 64
#define LAMBDA_INIT 0.8f
#define EPS_ 1e-6f

// exp(s*0.125) == exp2(s * 0.125*log2(e))
#define EXP2SCALE 0.18033688011112042f

typedef __attribute__((ext_vector_type(8))) short short8;   // 8 bf16 (4 VGPRs)
typedef __attribute__((ext_vector_type(4))) float floatx4;  // MFMA C/D

__device__ __forceinline__ unsigned short f2bf(float f) {
  unsigned u = __float_as_uint(f);
  u += 0x7FFFu + ((u >> 16) & 1u);   // RNE
  return (unsigned short)(u >> 16);
}

// pack two floats to bf16x2 with round-half-up: 2 adds + 1 v_perm
__device__ __forceinline__ unsigned pack_bf16x2(float a, float b) {
  unsigned ua = __float_as_uint(a) + 0x8000u;
  unsigned ub = __float_as_uint(b) + 0x8000u;
  return __builtin_amdgcn_perm(ub, ua, 0x07060302u);  // [ub_hi : ua_hi]
}

__device__ __forceinline__ void gl_lds16(const void* g, void* l) {
  __builtin_amdgcn_global_load_lds((const __attribute__((address_space(1))) void*)g,
                                   (__attribute__((address_space(3))) void*)l,
                                   16, 0, 0);
}

// ---------------------------------------------------------------------------
// Fused prep: bid<768 -> w_qkv^T tile; <1024 -> wo^T tile; else cast x->bf16.
// All paths block-uniform (no wave divergence).
// ---------------------------------------------------------------------------
__device__ __forceinline__ void transpose_cast_tile(const float* __restrict__ in,
                                                    unsigned short* __restrict__ out,
                                                    int R, int C, int bx, int by,
                                                    float tile[][65]) {
  const int tid = threadIdx.x;
  const int c0 = bx * 64, r0 = by * 64;
#pragma unroll
  for (int it = 0; it < 16; it++) {
    int e = tid + it * 256;
    int rr = e >> 6, cc = e & 63;
    tile[rr][cc] = in[(size_t)(r0 + rr) * C + c0 + cc];
  }
  __syncthreads();
#pragma unroll
  for (int it = 0; it < 16; it++) {
    int e = tid + it * 256;
    int rr = e >> 6, cc = e & 63;
    out[(size_t)(c0 + rr) * R + r0 + cc] = f2bf(tile[cc][rr]);
  }
}

__global__ __launch_bounds__(256) void prep(const float* __restrict__ x,
                                            const float* __restrict__ w_qkv,
                                            const float* __restrict__ wo,
                                            unsigned short* __restrict__ xB,
                                            unsigned short* __restrict__ WT,
                                            unsigned short* __restrict__ woT) {
  __shared__ float tile[64][65];
  const int bid = blockIdx.x;
  if (bid < 768) {
    transpose_cast_tile(w_qkv, WT, 1024, 3072, bid % 48, bid / 48, tile);
  } else if (bid < 1024) {
    const int b2 = bid - 768;
    transpose_cast_tile(wo, woT, 1024, 1024, b2 % 16, b2 / 16, tile);
  } else {
    // cast x (4096*1024 floats = 1048576 float4)
    for (int i = (bid - 1024) * 256 + threadIdx.x; i < 1048576; i += 1024 * 256) {
      float4 v = ((const float4*)x)[i];
      ushort4 w;
      w.x = f2bf(v.x); w.y = f2bf(v.y); w.z = f2bf(v.z); w.w = f2bf(v.w);
      ((ushort4*)xB)[i] = w;
    }
  }
}

// ---------------------------------------------------------------------------
// bf16 MFMA GEMM body: C[M][N] = A[M][K] @ Bt[N][K]^T. 128x128 tile, BK=64,
// global_load_lds w=16, XOR chunk swizzle.
// ---------------------------------------------------------------------------
template <bool BF16OUT>
__device__ __forceinline__ void gemm_bt_body(const unsigned short* __restrict__ A,
                                             const unsigned short* __restrict__ Bt,
                                             void* __restrict__ C, int M, int N,
                                             int K, int bx, int by,
                                             unsigned short* As, unsigned short* Bs) {
  const int tid = threadIdx.x;
  const int wave = tid >> 6, lane = tid & 63;
  const int lane15 = lane & 15, quad = lane >> 4;
  const int m0 = by * 128;
  const int n0 = bx * 128;
  const int wm = (wave & 1) * 64, wn = (wave >> 1) * 64;

  floatx4 acc[4][4];
#pragma unroll
  for (int mi = 0; mi < 4; mi++)
#pragma unroll
    for (int ni = 0; ni < 4; ni++) acc[mi][ni] = (floatx4)0.0f;

  const int rs = wave * 32 + (lane >> 3);
  const int cph = lane & 7;

  for (int k0 = 0; k0 < K; k0 += 64) {
    __syncthreads();
#pragma unroll
    for (int j = 0; j < 4; j++) {
      int r = rs + j * 8;
      int cl = cph ^ (r & 7);
      gl_lds16(A + (size_t)(m0 + r) * K + k0 + cl * 8, &As[(wave * 32 + j * 8) * 64]);
    }
#pragma unroll
    for (int j = 0; j < 4; j++) {
      int r = rs + j * 8;
      int cl = cph ^ (r & 7);
      gl_lds16(Bt + (size_t)(n0 + r) * K + k0 + cl * 8, &Bs[(wave * 32 + j * 8) * 64]);
    }
    __syncthreads();

#pragma unroll
    for (int ks = 0; ks < 2; ks++) {
      short8 af[4], bf[4];
#pragma unroll
      for (int mi = 0; mi < 4; mi++) {
        int r = wm + mi * 16 + lane15;
        int phys = (ks * 4 + quad) ^ (r & 7);
        af[mi] = *(const short8*)(&As[r * 64 + phys * 8]);
      }
#pragma unroll
      for (int ni = 0; ni < 4; ni++) {
        int r = wn + ni * 16 + lane15;
        int phys = (ks * 4 + quad) ^ (r & 7);
        bf[ni] = *(const short8*)(&Bs[r * 64 + phys * 8]);
      }
#pragma unroll
      for (int mi = 0; mi < 4; mi++)
#pragma unroll
        for (int ni = 0; ni < 4; ni++)
          acc[mi][ni] = __builtin_amdgcn_mfma_f32_16x16x32_bf16(af[mi], bf[ni],
                                                                acc[mi][ni], 0, 0, 0);
    }
  }

#pragma unroll
  for (int mi = 0; mi < 4; mi++)
#pragma unroll
    for (int ni = 0; ni < 4; ni++)
#pragma unroll
      for (int reg = 0; reg < 4; reg++) {
        int row = m0 + wm + mi * 16 + quad * 4 + reg;
        int col = n0 + wn + ni * 16 + lane15;
        float v = acc[mi][ni][reg];
        if (BF16OUT)
          ((unsigned short*)C)[(size_t)row * N + col] = f2bf(v);
        else
          ((float*)C)[(size_t)row * N + col] = v;
      }
}

// Fused: bid<512 -> qk GEMM [4096,2048,1024]; else vT GEMM [1024,4096,1024]
__global__ __launch_bounds__(256) void gemm_qkv(const unsigned short* __restrict__ xB,
                                                const unsigned short* __restrict__ WT,
                                                unsigned short* __restrict__ qkB,
                                                unsigned short* __restrict__ vTB) {
  __shared__ __align__(16) unsigned short As[128 * 64];
  __shared__ __align__(16) unsigned short Bs[128 * 64];
  const int bid = blockIdx.x;
  if (bid < 512) {
    gemm_bt_body<true>(xB, WT, (void*)qkB, 4096, 2048, 1024, bid & 15, bid >> 4, As, Bs);
  } else {
    const int b2 = bid - 512;
    gemm_bt_body<true>(WT + (size_t)2048 * 1024, xB, (void*)vTB, 1024, 4096, 1024,
                       b2 & 31, b2 >> 5, As, Bs);
  }
}

__global__ __launch_bounds__(256) void gemm2(const unsigned short* __restrict__ hidB,
                                             const unsigned short* __restrict__ woT,
                                             float* __restrict__ out) {
  __shared__ __align__(16) unsigned short As[128 * 64];
  __shared__ __align__(16) unsigned short Bs[128 * 64];
  gemm_bt_body<false>(hidB, woT, (void*)out, 4096, 1024, 1024, blockIdx.x,
                      blockIdx.y, As, Bs);
}

// ---------------------------------------------------------------------------
// S^T-form MFMA flash differential attention, DMA double-buffered (R7),
// VALU-slimmed: exp2 fold + v_perm bf16 pack; epilogue writes hidden (bf16,
// reference cat/transpose/view layout) directly — no reshape kernel.
// ---------------------------------------------------------------------------
__global__ __launch_bounds__(256) void flash_attn_mfma(
    const unsigned short* __restrict__ qkB, const unsigned short* __restrict__ vTB,
    const float* __restrict__ lq1, const float* __restrict__ lq2,
    const float* __restrict__ lk1, const float* __restrict__ lk2,
    const float* __restrict__ norm_w, unsigned short* __restrict__ hidB) {
  __shared__ __align__(16) unsigned short Qs[64 * 64];
  __shared__ __align__(16) unsigned short Ks[2][64 * 64];
  __shared__ __align__(16) unsigned short Vt[2][64 * 64];
  __shared__ __align__(16) unsigned short Ps[64 * 64];

  const int tid = threadIdx.x;
  const int wave = tid >> 6, lane = tid & 63;
  const int lane15 = lane & 15, quad = lane >> 4;
  const int m7 = lane15 & 7;
  const int bid = blockIdx.x;          // 1024 = B*H*32
  const int qt = bid & 31;
  const int h = (bid >> 5) & 15;
  const int b = bid >> 9;
  const int q0 = qt * 64;

  float a1 = 0.f, a2 = 0.f;
  for (int d = 0; d < HD_; d++) {
    a1 += lq1[d] * lk1[d];
    a2 += lq2[d] * lk2[d];
  }
  const float lam = __expf(a1) - __expf(a2) + LAMBDA_INIT;

  // DMA staging geometry: rows wave*16 + j*8 + (lane>>3); LDS dest fixed at
  // base + lane*16 -> phys chunk lane&7; logical chunk scl = (lane&7)^srow.
  const int srow = lane >> 3;
  const int scl = (lane & 7) ^ srow;

  const size_t kgbase = (size_t)b * S_ * 2048 + 1024 + h * 64;
  const size_t vgbase = (size_t)h * 64 * 4096 + b * 2048;

  // ---- stage Q (manual) + DMA tile 0 into buffer 0, one barrier ----
  {
    const int sr = tid >> 3, sp = tid & 7;
#pragma unroll
    for (int it = 0; it < 2; it++) {
      int r = sr + it * 32;
      int cl = sp ^ (r & 7);
      uint4 v = *(const uint4*)(qkB + (size_t)(b * S_ + q0 + r) * 2048 + h * 64 + cl * 8);
      *(uint4*)(Qs + r * 64 + sp * 8) = v;
    }
  }
#pragma unroll
  for (int j = 0; j < 2; j++) {
    int r = wave * 16 + j * 8 + srow;
    gl_lds16(qkB + kgbase + (size_t)r * 2048 + scl * 8, &Ks[0][(wave * 16 + j * 8) * 64]);
    gl_lds16(vTB + vgbase + (size_t)r * 4096 + scl * 8, &Vt[0][(wave * 16 + j * 8) * 64]);
  }
  __syncthreads();   // Qs visible + tile0 DMA drained

  const int myrow = wave * 16 + lane15;
  // Q as B-operand: B[n=q][k=d], logical chunk quad / 4+quad
  const short8 bq0 = *(const short8*)(Qs + myrow * 64 + ((quad) ^ m7) * 8);
  const short8 bq1 = *(const short8*)(Qs + myrow * 64 + ((4 + quad) ^ m7) * 8);

  floatx4 accO[2][4];   // [stream][nd]; D[q=quad*4+reg][d=nd*16+lane15]
  float lsum[2] = {0.f, 0.f};
#pragma unroll
  for (int s = 0; s < 2; s++)
#pragma unroll
    for (int nd = 0; nd < 4; nd++) accO[s][nd] = (floatx4)0.0f;
  const floatx4 zero4 = (floatx4)0.0f;

  for (int tt = 0; tt < 32; tt++) {
    const int cur = tt & 1, nxt = cur ^ 1;
    // issue next tile's DMA into the other buffer (overlaps this tile's compute)
    if (tt + 1 < 32) {
      const int t1 = (tt + 1) * 64;
#pragma unroll
      for (int j = 0; j < 2; j++) {
        int r = wave * 16 + j * 8 + srow;
        gl_lds16(qkB + kgbase + (size_t)(t1 + r) * 2048 + scl * 8,
                 &Ks[nxt][(wave * 16 + j * 8) * 64]);
        gl_lds16(vTB + vgbase + (size_t)r * 4096 + t1 + scl * 8,
                 &Vt[nxt][(wave * 16 + j * 8) * 64]);
      }
    }

    const unsigned short* Kc = Ks[cur];
    const unsigned short* Vc = Vt[cur];
#pragma unroll
    for (int s = 0; s < 2; s++) {
      const short8 bq = s ? bq1 : bq0;
      floatx4 sv[4];
#pragma unroll
      for (int nb = 0; nb < 4; nb++) {
        const short8 ak = *(const short8*)(Kc + (nb * 16 + lane15) * 64 +
                                           ((s * 4 + quad) ^ m7) * 8);
        sv[nb] = __builtin_amdgcn_mfma_f32_16x16x32_bf16(ak, bq, zero4, 0, 0, 0);
      }
      // exp + pack: lane holds S^T[t=nb*16+quad*4+reg][q=lane15]
      float ls = 0.f;
#pragma unroll
      for (int nb = 0; nb < 4; nb++) {
        float p0 = exp2f(sv[nb][0] * EXP2SCALE);
        float p1 = exp2f(sv[nb][1] * EXP2SCALE);
        float p2 = exp2f(sv[nb][2] * EXP2SCALE);
        float p3 = exp2f(sv[nb][3] * EXP2SCALE);
        ls += (p0 + p1) + (p2 + p3);
        unsigned lo = pack_bf16x2(p0, p1);
        unsigned hi = pack_bf16x2(p2, p3);
        int cl = nb * 2 + (quad >> 1);
        uint2* dst = (uint2*)(Ps + myrow * 64 + ((cl ^ m7) * 8) + (quad & 1) * 4);
        *dst = make_uint2(lo, hi);
      }
      lsum[s] += ls;
      // PV: A = P row myrow (own wave's write, in-order DS), B = V^T
#pragma unroll
      for (int ks = 0; ks < 2; ks++) {
        const short8 ap = *(const short8*)(Ps + myrow * 64 + ((ks * 4 + quad) ^ m7) * 8);
#pragma unroll
        for (int nd = 0; nd < 4; nd++) {
          const short8 bv = *(const short8*)(Vc + (nd * 16 + lane15) * 64 +
                                             ((ks * 4 + quad) ^ m7) * 8);
          accO[s][nd] = __builtin_amdgcn_mfma_f32_16x16x32_bf16(ap, bv,
                                                                accO[s][nd], 0, 0, 0);
        }
      }
    }
    // single barrier: waits compute reads of cur AND drains next-tile DMA
    __syncthreads();
  }

  // ---- epilogue: combine, RMSNorm, write hidden bf16 directly at
  // cat/transpose/view offsets: idx = b*S*E + d*H*S + h*S + t ----
#pragma unroll
  for (int s = 0; s < 2; s++) {
    lsum[s] += __shfl_xor(lsum[s], 16, 64);
    lsum[s] += __shfl_xor(lsum[s], 32, 64);
  }
  const float* nw = norm_w + h * HD_;
  float nwv[4];
#pragma unroll
  for (int nd = 0; nd < 4; nd++) nwv[nd] = nw[nd * 16 + lane15];

  unsigned short* dstB = hidB + (size_t)b * (S_ * E_) + h * S_;
#pragma unroll
  for (int r4 = 0; r4 < 4; r4++) {
    const int qloc = quad * 4 + r4;
    const float l1 = __shfl(lsum[0], qloc, 64);
    const float l2 = __shfl(lsum[1], qloc, 64);
    const float inv1 = 1.0f / l1;
    const float c2 = lam / l2;
    float o[4];
    float ss = 0.f;
#pragma unroll
    for (int nd = 0; nd < 4; nd++) {
      o[nd] = accO[0][nd][r4] * inv1 - accO[1][nd][r4] * c2;
      ss += o[nd] * o[nd];
    }
#pragma unroll
    for (int msk = 1; msk <= 8; msk <<= 1) ss += __shfl_xor(ss, msk, 64);
    const float rsc = (1.0f - LAMBDA_INIT) * rsqrtf(ss * (1.0f / 64.0f) + EPS_);
    const int trow = q0 + wave * 16 + qloc;
#pragma unroll
    for (int nd = 0; nd < 4; nd++)
      dstB[(size_t)(nd * 16 + lane15) * (H_ * S_) + trow] = f2bf(o[nd] * rsc * nwv[nd]);
  }
}

// ---------------------------------------------------------------------------
extern "C" void kernel_launch(void* const* d_in, const int* in_sizes, int n_in,
                              void* d_out, int out_size, void* d_ws, size_t ws_size,
                              hipStream_t stream) {
  const float* x = (const float*)d_in[0];
  const float* w_qkv = (const float*)d_in[1];
  const float* wo = (const float*)d_in[2];
  const float* lq1 = (const float*)d_in[3];
  const float* lq2 = (const float*)d_in[4];
  const float* lk1 = (const float*)d_in[5];
  const float* lk2 = (const float*)d_in[6];
  const float* norm_w = (const float*)d_in[7];
  float* out = (float*)d_out;

  unsigned short* xB = (unsigned short*)d_ws;             // 4096*1024
  unsigned short* WT = xB + (size_t)4096 * 1024;          // 3072*1024 (w_qkv^T)
  unsigned short* woT = WT + (size_t)3072 * 1024;         // 1024*1024
  unsigned short* qkB = woT + (size_t)1024 * 1024;        // 4096*2048
  unsigned short* vTB = qkB + (size_t)4096 * 2048;        // 1024*4096
  unsigned short* hidB = vTB + (size_t)1024 * 4096;       // 4096*1024

  // 0) fused prep: casts + transposes (1 launch)
  prep<<<2048, 256, 0, stream>>>(x, w_qkv, wo, xB, WT, woT);
  // 1) fused qk GEMM + vT GEMM (1 launch)
  gemm_qkv<<<768, 256, 0, stream>>>(xB, WT, qkB, vTB);
  // 2) MFMA differential flash attention + RMSNorm + fused reshape -> hidB
  flash_attn_mfma<<<B_ * H_ * (S_ / 64), 256, 0, stream>>>(qkB, vTB, lq1, lq2, lk1,
                                                           lk2, norm_w, hidB);
  // 3) out = hidden @ wo (fp32 out)
  gemm2<<<dim3(1024 / 128, 4096 / 128), 256, 0, stream>>>(hidB, woT, out);
}